// Round 1
// baseline (1246.702 us; speedup 1.0000x reference)
//
#include <hip/hip_runtime.h>
#include <hip/hip_bf16.h>

// Windowed 3D attention transformer block, MI355X bf16-MFMA implementation.
// Residual stream fp32; GEMM/attention compute bf16 in, fp32 accumulate.

typedef __attribute__((ext_vector_type(4))) short short4v;
typedef __attribute__((ext_vector_type(8))) short short8v;
typedef __attribute__((ext_vector_type(4))) float f32x4;

__device__ __forceinline__ unsigned short f2bf(float f) {
  unsigned u = __float_as_uint(f);
  u += 0x7fffu + ((u >> 16) & 1u);   // RNE; inputs finite
  return (unsigned short)(u >> 16);
}

// ---------------- weight prep: fp32 KxN -> bf16 NxK (transposed) ----------
__global__ __launch_bounds__(256)
void wprep_kernel(const float* __restrict__ w, unsigned short* __restrict__ wt,
                  int kbits, int total, int N) {
  int idx = blockIdx.x * 256 + threadIdx.x;
  if (idx >= total) return;
  int K = 1 << kbits;
  int n = idx >> kbits, kk = idx & (K - 1);
  wt[idx] = f2bf(w[(long)kk * N + n]);
}

// ---------------- LayerNorm (one wave per 512-elem row) --------------------
// gather=1: row index is window-layout; source gathered from original coords
// (cyclic shift + window partition fused into the index mapping).
__global__ __launch_bounds__(256)
void ln_kernel(const float* __restrict__ src, const float* __restrict__ g,
               const float* __restrict__ bb, unsigned short* __restrict__ dst,
               const int gather) {
  const int lane = threadIdx.x & 63;
  const int row = blockIdx.x * 4 + (threadIdx.x >> 6);
  long srow;
  if (gather) {
    int n = row & 63, win = row >> 6;
    int w0 = win & 7, h0 = (win >> 3) & 7, d0 = (win >> 6) & 7, b2 = win >> 9;
    int dx = n & 3, dy = (n >> 2) & 3, dz = n >> 4;
    int od = (d0 * 4 + dz + 2) & 31, oh = (h0 * 4 + dy + 2) & 31, ow = (w0 * 4 + dx + 2) & 31;
    srow = (((long)b2 * 32 + od) * 32 + oh) * 32 + ow;
  } else {
    srow = row;
  }
  const float4* sp = (const float4*)(src + srow * 512);
  float4 x0 = sp[lane], x1 = sp[lane + 64];
  float sum = x0.x + x0.y + x0.z + x0.w + x1.x + x1.y + x1.z + x1.w;
  float sq  = x0.x*x0.x + x0.y*x0.y + x0.z*x0.z + x0.w*x0.w
            + x1.x*x1.x + x1.y*x1.y + x1.z*x1.z + x1.w*x1.w;
#pragma unroll
  for (int off = 1; off < 64; off <<= 1) {
    sum += __shfl_xor(sum, off, 64);
    sq  += __shfl_xor(sq, off, 64);
  }
  float mean = sum * (1.0f / 512.0f);
  float var  = sq * (1.0f / 512.0f) - mean * mean;
  float rstd = rsqrtf(var + 1e-5f);
  float4 g0 = ((const float4*)g)[lane], g1 = ((const float4*)g)[lane + 64];
  float4 b0 = ((const float4*)bb)[lane], b1v = ((const float4*)bb)[lane + 64];
  ushort4 o0, o1;
  o0.x = f2bf((x0.x - mean) * rstd * g0.x + b0.x);
  o0.y = f2bf((x0.y - mean) * rstd * g0.y + b0.y);
  o0.z = f2bf((x0.z - mean) * rstd * g0.z + b0.z);
  o0.w = f2bf((x0.w - mean) * rstd * g0.w + b0.w);
  o1.x = f2bf((x1.x - mean) * rstd * g1.x + b1v.x);
  o1.y = f2bf((x1.y - mean) * rstd * g1.y + b1v.y);
  o1.z = f2bf((x1.z - mean) * rstd * g1.z + b1v.z);
  o1.w = f2bf((x1.w - mean) * rstd * g1.w + b1v.w);
  *(ushort4*)(dst + (long)row * 512 + lane * 4) = o0;
  *(ushort4*)(dst + (long)row * 512 + 256 + lane * 4) = o1;
}

// ---------------- GEMM: C[M,N] = A[M,K](bf16) * Bt[N,K]^T + bias ----------
// 128x128 block tile, BK=32, 4 waves each computing a 64x64 quadrant with
// 4x4 v_mfma_f32_16x16x32_bf16. LDS row stride 44 ushorts -> conflict-free
// b64 fragment reads. Epilogues:
//  EPI 0: qkv scatter -> q[u][n][hd], k[u][n][hd], v[u][hd][n]  (bf16)
//  EPI 1: + x residual, scatter to original coords -> xo (fp32)
//  EPI 2: exact GELU -> hid (bf16)
//  EPI 3: + xo residual -> out (fp32)
#define LDSP 44

template <int EPI>
__global__ __launch_bounds__(256)
void gemm_bt(const unsigned short* __restrict__ A,
             const unsigned short* __restrict__ Bt,
             const float* __restrict__ bias, int K,
             void* __restrict__ out0,
             unsigned short* __restrict__ out1,
             unsigned short* __restrict__ out2,
             const float* __restrict__ res) {
  __shared__ unsigned short As[128 * LDSP];
  __shared__ unsigned short Bs[128 * LDSP];
  const int tid = threadIdx.x;
  const int lane = tid & 63;
  const int wave = tid >> 6;
  const int quad = lane >> 4;
  const int l15 = lane & 15;
  const int wm = (wave >> 1) << 6;
  const int wn = (wave & 1) << 6;
  const long row0 = (long)blockIdx.y * 128;
  const long col0 = (long)blockIdx.x * 128;

  f32x4 acc[4][4] = {};

  const int sr = tid >> 2;   // 0..63 staging row
  const int sc = tid & 3;    // 16B chunk within 64B row-slice

  for (int kk = 0; kk < K; kk += 32) {
    __syncthreads();
    {
      const unsigned long long* ga0 = (const unsigned long long*)(A + (row0 + sr) * K + kk + sc * 8);
      const unsigned long long* ga1 = (const unsigned long long*)(A + (row0 + sr + 64) * K + kk + sc * 8);
      const unsigned long long* gb0 = (const unsigned long long*)(Bt + (col0 + sr) * K + kk + sc * 8);
      const unsigned long long* gb1 = (const unsigned long long*)(Bt + (col0 + sr + 64) * K + kk + sc * 8);
      unsigned long long a0l = ga0[0], a0h = ga0[1];
      unsigned long long a1l = ga1[0], a1h = ga1[1];
      unsigned long long b0l = gb0[0], b0h = gb0[1];
      unsigned long long b1l = gb1[0], b1h = gb1[1];
      *(unsigned long long*)&As[sr * LDSP + sc * 8]            = a0l;
      *(unsigned long long*)&As[sr * LDSP + sc * 8 + 4]        = a0h;
      *(unsigned long long*)&As[(sr + 64) * LDSP + sc * 8]     = a1l;
      *(unsigned long long*)&As[(sr + 64) * LDSP + sc * 8 + 4] = a1h;
      *(unsigned long long*)&Bs[sr * LDSP + sc * 8]            = b0l;
      *(unsigned long long*)&Bs[sr * LDSP + sc * 8 + 4]        = b0h;
      *(unsigned long long*)&Bs[(sr + 64) * LDSP + sc * 8]     = b1l;
      *(unsigned long long*)&Bs[(sr + 64) * LDSP + sc * 8 + 4] = b1h;
    }
    __syncthreads();
    short4v alo[4], ahi[4], blo[4], bhi[4];
#pragma unroll
    for (int t = 0; t < 4; ++t) {
      const unsigned short* pa = &As[(wm + t * 16 + l15) * LDSP + quad * 8];
      alo[t] = *(const short4v*)pa;
      ahi[t] = *(const short4v*)(pa + 4);
      const unsigned short* pb = &Bs[(wn + t * 16 + l15) * LDSP + quad * 8];
      blo[t] = *(const short4v*)pb;
      bhi[t] = *(const short4v*)(pb + 4);
    }
#pragma unroll
    for (int mt = 0; mt < 4; ++mt) {
      short8v af = __builtin_shufflevector(alo[mt], ahi[mt], 0, 1, 2, 3, 4, 5, 6, 7);
#pragma unroll
      for (int nt = 0; nt < 4; ++nt) {
        short8v bf = __builtin_shufflevector(blo[nt], bhi[nt], 0, 1, 2, 3, 4, 5, 6, 7);
        acc[mt][nt] = __builtin_amdgcn_mfma_f32_16x16x32_bf16(af, bf, acc[mt][nt], 0, 0, 0);
      }
    }
  }

#pragma unroll
  for (int mt = 0; mt < 4; ++mt) {
#pragma unroll
    for (int nt = 0; nt < 4; ++nt) {
#pragma unroll
      for (int r = 0; r < 4; ++r) {
        const long gr = row0 + wm + mt * 16 + quad * 4 + r;
        const long gc = col0 + wn + nt * 16 + l15;
        float val = acc[mt][nt][r] + bias[gc];
        if (EPI == 0) {
          int which = (int)(gc >> 9), rem = (int)gc & 511;
          int head = rem >> 6, hd = rem & 63;
          long win = gr >> 6, n = gr & 63;
          long base = (win * 8 + head) * 4096;
          unsigned short bv = f2bf(val);
          if (which == 0)      ((unsigned short*)out0)[base + n * 64 + hd] = bv;
          else if (which == 1) out1[base + n * 64 + hd] = bv;
          else                 out2[base + hd * 64 + n] = bv;   // v transposed
        } else if (EPI == 1) {
          int win = (int)(gr >> 6), n = (int)gr & 63;
          int w0 = win & 7, h0 = (win >> 3) & 7, d0 = (win >> 6) & 7, b2 = win >> 9;
          int dx = n & 3, dy = (n >> 2) & 3, dz = n >> 4;
          int od = (d0 * 4 + dz + 2) & 31, oh = (h0 * 4 + dy + 2) & 31, ow = (w0 * 4 + dx + 2) & 31;
          long addr = ((((long)b2 * 32 + od) * 32 + oh) * 32 + ow) * 512 + gc;
          ((float*)out0)[addr] = res[addr] + val;
        } else if (EPI == 2) {
          float ge = 0.5f * val * (1.0f + erff(val * 0.70710678118654752f));
          ((unsigned short*)out0)[gr * 2048 + gc] = f2bf(ge);
        } else {
          long addr = gr * 512 + gc;
          ((float*)out0)[addr] = res[addr] + val;
        }
      }
    }
  }
}

// ---------------- attention: one wave per (window, head) -------------------
// q,k: [unit][n][hd] bf16; v: [unit][hd][n] bf16 (transposed at QKV epilogue)
// Fragments loaded directly from global (layouts match MFMA operand maps);
// P (64x64) round-trips LDS for C-layout -> A-layout.
__global__ __launch_bounds__(256)
void attn_kernel(const unsigned short* __restrict__ q,
                 const unsigned short* __restrict__ k,
                 const unsigned short* __restrict__ vt,
                 unsigned short* __restrict__ out) {
  __shared__ unsigned short Ps[4][64 * 72];
  const int lane = threadIdx.x & 63;
  const int wave = threadIdx.x >> 6;
  const int quad = lane >> 4;
  const int l15 = lane & 15;
  const int unit = blockIdx.x * 4 + wave;
  const int win = unit >> 3;
  const int head = unit & 7;
  const long base = (long)unit * 4096;

  f32x4 s[4][4] = {};
#pragma unroll
  for (int kk = 0; kk < 64; kk += 32) {
    short8v a[4], b[4];
#pragma unroll
    for (int t = 0; t < 4; ++t) {
      a[t] = *(const short8v*)(q + base + (t * 16 + l15) * 64 + kk + quad * 8);
      b[t] = *(const short8v*)(k + base + (t * 16 + l15) * 64 + kk + quad * 8);
    }
#pragma unroll
    for (int mt = 0; mt < 4; ++mt)
#pragma unroll
      for (int nt = 0; nt < 4; ++nt)
        s[mt][nt] = __builtin_amdgcn_mfma_f32_16x16x32_bf16(a[mt], b[nt], s[mt][nt], 0, 0, 0);
  }

  float lrow[4][4];
#pragma unroll
  for (int mt = 0; mt < 4; ++mt) {
#pragma unroll
    for (int r = 0; r < 4; ++r) {
      float v0 = s[mt][0][r] * 0.125f, v1 = s[mt][1][r] * 0.125f;
      float v2 = s[mt][2][r] * 0.125f, v3 = s[mt][3][r] * 0.125f;
      float mx = fmaxf(fmaxf(v0, v1), fmaxf(v2, v3));
#pragma unroll
      for (int off = 1; off < 16; off <<= 1) mx = fmaxf(mx, __shfl_xor(mx, off, 64));
      v0 = __expf(v0 - mx); v1 = __expf(v1 - mx);
      v2 = __expf(v2 - mx); v3 = __expf(v3 - mx);
      float sm = v0 + v1 + v2 + v3;
#pragma unroll
      for (int off = 1; off < 16; off <<= 1) sm += __shfl_xor(sm, off, 64);
      lrow[mt][r] = sm;
      int row = mt * 16 + quad * 4 + r;
      Ps[wave][row * 72 + 0 + l15]  = f2bf(v0);
      Ps[wave][row * 72 + 16 + l15] = f2bf(v1);
      Ps[wave][row * 72 + 32 + l15] = f2bf(v2);
      Ps[wave][row * 72 + 48 + l15] = f2bf(v3);
    }
  }
  __syncthreads();

  f32x4 o[4][4] = {};
#pragma unroll
  for (int kk = 0; kk < 64; kk += 32) {
    short8v a[4], b[4];
#pragma unroll
    for (int t = 0; t < 4; ++t) {
      a[t] = *(const short8v*)(&Ps[wave][(t * 16 + l15) * 72 + kk + quad * 8]);
      b[t] = *(const short8v*)(vt + base + (t * 16 + l15) * 64 + kk + quad * 8);
    }
#pragma unroll
    for (int mt = 0; mt < 4; ++mt)
#pragma unroll
      for (int nt = 0; nt < 4; ++nt)
        o[mt][nt] = __builtin_amdgcn_mfma_f32_16x16x32_bf16(a[mt], b[nt], o[mt][nt], 0, 0, 0);
  }

#pragma unroll
  for (int mt = 0; mt < 4; ++mt)
#pragma unroll
    for (int nt = 0; nt < 4; ++nt)
#pragma unroll
      for (int r = 0; r < 4; ++r) {
        int row = mt * 16 + quad * 4 + r;
        int col = nt * 16 + l15;
        float val = o[mt][nt][r] / lrow[mt][r];
        out[((long)win * 64 + row) * 512 + head * 64 + col] = f2bf(val);
      }
}

// ---------------- launch ---------------------------------------------------
extern "C" void kernel_launch(void* const* d_in, const int* in_sizes, int n_in,
                              void* d_out, int out_size, void* d_ws, size_t ws_size,
                              hipStream_t stream) {
  const float* x      = (const float*)d_in[0];
  const float* ln1_g  = (const float*)d_in[1];
  const float* ln1_b  = (const float*)d_in[2];
  const float* qkv_w  = (const float*)d_in[3];
  const float* qkv_b  = (const float*)d_in[4];
  const float* proj_w = (const float*)d_in[5];
  const float* proj_b = (const float*)d_in[6];
  const float* ln2_g  = (const float*)d_in[7];
  const float* ln2_b  = (const float*)d_in[8];
  const float* w1     = (const float*)d_in[9];
  const float* b1     = (const float*)d_in[10];
  const float* w2     = (const float*)d_in[11];
  const float* b2     = (const float*)d_in[12];

  // workspace layout (bytes); hid overlays attn_out+q+k+v (dead after proj)
  char* ws = (char*)d_ws;
  unsigned short* wt_qkv  = (unsigned short*)(ws + 0);          // 1536x512 bf16
  unsigned short* wt_proj = (unsigned short*)(ws + 1572864);    // 512x512
  unsigned short* wt_1    = (unsigned short*)(ws + 2097152);    // 2048x512
  unsigned short* wt_2    = (unsigned short*)(ws + 4194304);    // 512x2048
  float*          xo      = (float*)(ws + 8388608);             // 128 MiB fp32
  unsigned short* h       = (unsigned short*)(ws + 142606336);  // 64 MiB bf16 (h, then h2)
  unsigned short* attno   = (unsigned short*)(ws + 209715200);  // 64 MiB
  unsigned short* qb      = (unsigned short*)(ws + 276824064);  // 64 MiB
  unsigned short* kb      = (unsigned short*)(ws + 343932928);  // 64 MiB
  unsigned short* vb      = (unsigned short*)(ws + 411041792);  // 64 MiB
  unsigned short* hid     = (unsigned short*)(ws + 209715200);  // 256 MiB overlay
  float* out = (float*)d_out;

  wprep_kernel<<<3072, 256, 0, stream>>>(qkv_w, wt_qkv, 9, 512 * 1536, 1536);
  wprep_kernel<<<1024, 256, 0, stream>>>(proj_w, wt_proj, 9, 512 * 512, 512);
  wprep_kernel<<<4096, 256, 0, stream>>>(w1, wt_1, 9, 512 * 2048, 2048);
  wprep_kernel<<<4096, 256, 0, stream>>>(w2, wt_2, 11, 2048 * 512, 512);

  ln_kernel<<<16384, 256, 0, stream>>>(x, ln1_g, ln1_b, h, 1);
  gemm_bt<0><<<dim3(12, 512), 256, 0, stream>>>(h, wt_qkv, qkv_b, 512, qb, kb, vb, nullptr);
  attn_kernel<<<2048, 256, 0, stream>>>(qb, kb, vb, attno);
  gemm_bt<1><<<dim3(4, 512), 256, 0, stream>>>(attno, wt_proj, proj_b, 512, xo, nullptr, nullptr, x);
  ln_kernel<<<16384, 256, 0, stream>>>(xo, ln2_g, ln2_b, h, 0);
  gemm_bt<2><<<dim3(16, 512), 256, 0, stream>>>(h, wt_1, b1, 512, hid, nullptr, nullptr, nullptr);
  gemm_bt<3><<<dim3(4, 512), 256, 0, stream>>>(hid, wt_2, b2, 2048, out, nullptr, nullptr, xo);
}

// Round 2
// 1208.151 us; speedup vs baseline: 1.0319x; 1.0319x over previous
//
#include <hip/hip_runtime.h>
#include <hip/hip_bf16.h>

// Windowed 3D attention transformer block, MI355X bf16-MFMA implementation.
// Residual stream fp32; GEMM/attention compute bf16 in, fp32 accumulate.
// R1: gemm_bt restructured to m97 pattern — global_load_lds width=16 staging
// into contiguous 128x32 LDS tiles, XOR-swizzled chunks (conflict-free b128).

typedef __attribute__((ext_vector_type(4))) short short4v;
typedef __attribute__((ext_vector_type(8))) short short8v;
typedef __attribute__((ext_vector_type(4))) float f32x4;

__device__ __forceinline__ unsigned short f2bf(float f) {
  unsigned u = __float_as_uint(f);
  u += 0x7fffu + ((u >> 16) & 1u);   // RNE; inputs finite
  return (unsigned short)(u >> 16);
}

// async 16B global->LDS DMA; LDS dest = wave-uniform base + lane*16
__device__ __forceinline__ void gload_lds16(const unsigned short* g, unsigned short* l) {
  __builtin_amdgcn_global_load_lds(
      (const __attribute__((address_space(1))) unsigned int*)g,
      (__attribute__((address_space(3))) unsigned int*)l, 16, 0, 0);
}

// ---------------- weight prep: fp32 KxN -> bf16 NxK (transposed) ----------
__global__ __launch_bounds__(256)
void wprep_kernel(const float* __restrict__ w, unsigned short* __restrict__ wt,
                  int kbits, int total, int N) {
  int idx = blockIdx.x * 256 + threadIdx.x;
  if (idx >= total) return;
  int K = 1 << kbits;
  int n = idx >> kbits, kk = idx & (K - 1);
  wt[idx] = f2bf(w[(long)kk * N + n]);
}

// ---------------- LayerNorm (one wave per 512-elem row) --------------------
__global__ __launch_bounds__(256)
void ln_kernel(const float* __restrict__ src, const float* __restrict__ g,
               const float* __restrict__ bb, unsigned short* __restrict__ dst,
               const int gather) {
  const int lane = threadIdx.x & 63;
  const int row = blockIdx.x * 4 + (threadIdx.x >> 6);
  long srow;
  if (gather) {
    int n = row & 63, win = row >> 6;
    int w0 = win & 7, h0 = (win >> 3) & 7, d0 = (win >> 6) & 7, b2 = win >> 9;
    int dx = n & 3, dy = (n >> 2) & 3, dz = n >> 4;
    int od = (d0 * 4 + dz + 2) & 31, oh = (h0 * 4 + dy + 2) & 31, ow = (w0 * 4 + dx + 2) & 31;
    srow = (((long)b2 * 32 + od) * 32 + oh) * 32 + ow;
  } else {
    srow = row;
  }
  const float4* sp = (const float4*)(src + srow * 512);
  float4 x0 = sp[lane], x1 = sp[lane + 64];
  float sum = x0.x + x0.y + x0.z + x0.w + x1.x + x1.y + x1.z + x1.w;
  float sq  = x0.x*x0.x + x0.y*x0.y + x0.z*x0.z + x0.w*x0.w
            + x1.x*x1.x + x1.y*x1.y + x1.z*x1.z + x1.w*x1.w;
#pragma unroll
  for (int off = 1; off < 64; off <<= 1) {
    sum += __shfl_xor(sum, off, 64);
    sq  += __shfl_xor(sq, off, 64);
  }
  float mean = sum * (1.0f / 512.0f);
  float var  = sq * (1.0f / 512.0f) - mean * mean;
  float rstd = rsqrtf(var + 1e-5f);
  float4 g0 = ((const float4*)g)[lane], g1 = ((const float4*)g)[lane + 64];
  float4 b0 = ((const float4*)bb)[lane], b1v = ((const float4*)bb)[lane + 64];
  ushort4 o0, o1;
  o0.x = f2bf((x0.x - mean) * rstd * g0.x + b0.x);
  o0.y = f2bf((x0.y - mean) * rstd * g0.y + b0.y);
  o0.z = f2bf((x0.z - mean) * rstd * g0.z + b0.z);
  o0.w = f2bf((x0.w - mean) * rstd * g0.w + b0.w);
  o1.x = f2bf((x1.x - mean) * rstd * g1.x + b1v.x);
  o1.y = f2bf((x1.y - mean) * rstd * g1.y + b1v.y);
  o1.z = f2bf((x1.z - mean) * rstd * g1.z + b1v.z);
  o1.w = f2bf((x1.w - mean) * rstd * g1.w + b1v.w);
  *(ushort4*)(dst + (long)row * 512 + lane * 4) = o0;
  *(ushort4*)(dst + (long)row * 512 + 256 + lane * 4) = o1;
}

// ---------------- GEMM: C[M,N] = A[M,K](bf16) * Bt[N,K]^T + bias ----------
// 128x128 block tile, BK=32, 4 waves, 4x4 v_mfma_f32_16x16x32_bf16 each.
// Staging: global_load_lds 16B, contiguous 128x32-ushort LDS tiles.
// Swizzle: LDS[r][chunk] holds global chunk (chunk ^ ((r>>1)&3)) -> the
// 16-lane b128 fragment read hits all 8 bank groups exactly twice (free).
template <int EPI>
__global__ __launch_bounds__(256)
void gemm_bt(const unsigned short* __restrict__ A,
             const unsigned short* __restrict__ Bt,
             const float* __restrict__ bias, int K,
             void* __restrict__ out0,
             unsigned short* __restrict__ out1,
             unsigned short* __restrict__ out2,
             const float* __restrict__ res) {
  __shared__ unsigned short As[128 * 32];
  __shared__ unsigned short Bs[128 * 32];
  const int tid = threadIdx.x;
  const int lane = tid & 63;
  const int wv = tid >> 6;
  const int quad = lane >> 4;
  const int l15 = lane & 15;
  const int wm = (wv >> 1) << 6;
  const int wn = (wv & 1) << 6;
  const long row0 = (long)blockIdx.y * 128;
  const long col0 = (long)blockIdx.x * 128;

  f32x4 acc[4][4] = {};

  // staging geometry: wave w stages rows [c*64 + w*16, +16), lane covers
  // row (lane>>2), chunk (lane&3); global chunk is XOR-swizzled.
  const int srw = lane >> 2;         // 0..15 row within wave's slice
  const int sch = lane & 3;          // LDS chunk this lane's 16B lands in

  for (int kk = 0; kk < K; kk += 32) {
    __syncthreads();
#pragma unroll
    for (int c = 0; c < 2; ++c) {
      const int r = c * 64 + wv * 16 + srw;          // tile-relative row
      const int gch = sch ^ ((r >> 1) & 3);          // swizzled source chunk
      gload_lds16(A + (row0 + r) * K + kk + gch * 8, &As[(c * 64 + wv * 16) * 32]);
      gload_lds16(Bt + (col0 + r) * K + kk + gch * 8, &Bs[(c * 64 + wv * 16) * 32]);
    }
    __syncthreads();
    short8v af[4], bf[4];
#pragma unroll
    for (int t = 0; t < 4; ++t) {
      const int ra = wm + t * 16 + l15;
      af[t] = *(const short8v*)&As[ra * 32 + (quad ^ ((ra >> 1) & 3)) * 8];
      const int rb = wn + t * 16 + l15;
      bf[t] = *(const short8v*)&Bs[rb * 32 + (quad ^ ((rb >> 1) & 3)) * 8];
    }
#pragma unroll
    for (int mt = 0; mt < 4; ++mt)
#pragma unroll
      for (int nt = 0; nt < 4; ++nt)
        acc[mt][nt] = __builtin_amdgcn_mfma_f32_16x16x32_bf16(af[mt], bf[nt], acc[mt][nt], 0, 0, 0);
  }

#pragma unroll
  for (int mt = 0; mt < 4; ++mt) {
#pragma unroll
    for (int nt = 0; nt < 4; ++nt) {
#pragma unroll
      for (int r = 0; r < 4; ++r) {
        const long gr = row0 + wm + mt * 16 + quad * 4 + r;
        const long gc = col0 + wn + nt * 16 + l15;
        float val = acc[mt][nt][r] + bias[gc];
        if (EPI == 0) {
          int which = (int)(gc >> 9), rem = (int)gc & 511;
          int head = rem >> 6, hd = rem & 63;
          long win = gr >> 6, n = gr & 63;
          long base = (win * 8 + head) * 4096;
          unsigned short bv = f2bf(val);
          if (which == 0)      ((unsigned short*)out0)[base + n * 64 + hd] = bv;
          else if (which == 1) out1[base + n * 64 + hd] = bv;
          else                 out2[base + hd * 64 + n] = bv;   // v transposed
        } else if (EPI == 1) {
          int win = (int)(gr >> 6), n = (int)gr & 63;
          int w0 = win & 7, h0 = (win >> 3) & 7, d0 = (win >> 6) & 7, b2 = win >> 9;
          int dx = n & 3, dy = (n >> 2) & 3, dz = n >> 4;
          int od = (d0 * 4 + dz + 2) & 31, oh = (h0 * 4 + dy + 2) & 31, ow = (w0 * 4 + dx + 2) & 31;
          long addr = ((((long)b2 * 32 + od) * 32 + oh) * 32 + ow) * 512 + gc;
          ((float*)out0)[addr] = res[addr] + val;
        } else if (EPI == 2) {
          float ge = 0.5f * val * (1.0f + erff(val * 0.70710678118654752f));
          ((unsigned short*)out0)[gr * 2048 + gc] = f2bf(ge);
        } else {
          long addr = gr * 512 + gc;
          ((float*)out0)[addr] = res[addr] + val;
        }
      }
    }
  }
}

// ---------------- attention: one wave per (window, head) -------------------
__global__ __launch_bounds__(256)
void attn_kernel(const unsigned short* __restrict__ q,
                 const unsigned short* __restrict__ k,
                 const unsigned short* __restrict__ vt,
                 unsigned short* __restrict__ out) {
  __shared__ unsigned short Ps[4][64 * 72];
  const int lane = threadIdx.x & 63;
  const int wave = threadIdx.x >> 6;
  const int quad = lane >> 4;
  const int l15 = lane & 15;
  const int unit = blockIdx.x * 4 + wave;
  const int win = unit >> 3;
  const int head = unit & 7;
  const long base = (long)unit * 4096;

  f32x4 s[4][4] = {};
#pragma unroll
  for (int kk = 0; kk < 64; kk += 32) {
    short8v a[4], b[4];
#pragma unroll
    for (int t = 0; t < 4; ++t) {
      a[t] = *(const short8v*)(q + base + (t * 16 + l15) * 64 + kk + quad * 8);
      b[t] = *(const short8v*)(k + base + (t * 16 + l15) * 64 + kk + quad * 8);
    }
#pragma unroll
    for (int mt = 0; mt < 4; ++mt)
#pragma unroll
      for (int nt = 0; nt < 4; ++nt)
        s[mt][nt] = __builtin_amdgcn_mfma_f32_16x16x32_bf16(a[mt], b[nt], s[mt][nt], 0, 0, 0);
  }

  float lrow[4][4];
#pragma unroll
  for (int mt = 0; mt < 4; ++mt) {
#pragma unroll
    for (int r = 0; r < 4; ++r) {
      float v0 = s[mt][0][r] * 0.125f, v1 = s[mt][1][r] * 0.125f;
      float v2 = s[mt][2][r] * 0.125f, v3 = s[mt][3][r] * 0.125f;
      float mx = fmaxf(fmaxf(v0, v1), fmaxf(v2, v3));
#pragma unroll
      for (int off = 1; off < 16; off <<= 1) mx = fmaxf(mx, __shfl_xor(mx, off, 64));
      v0 = __expf(v0 - mx); v1 = __expf(v1 - mx);
      v2 = __expf(v2 - mx); v3 = __expf(v3 - mx);
      float sm = v0 + v1 + v2 + v3;
#pragma unroll
      for (int off = 1; off < 16; off <<= 1) sm += __shfl_xor(sm, off, 64);
      lrow[mt][r] = sm;
      int row = mt * 16 + quad * 4 + r;
      Ps[wave][row * 72 + 0 + l15]  = f2bf(v0);
      Ps[wave][row * 72 + 16 + l15] = f2bf(v1);
      Ps[wave][row * 72 + 32 + l15] = f2bf(v2);
      Ps[wave][row * 72 + 48 + l15] = f2bf(v3);
    }
  }
  __syncthreads();

  f32x4 o[4][4] = {};
#pragma unroll
  for (int kk = 0; kk < 64; kk += 32) {
    short8v a[4], b[4];
#pragma unroll
    for (int t = 0; t < 4; ++t) {
      a[t] = *(const short8v*)(&Ps[wave][(t * 16 + l15) * 72 + kk + quad * 8]);
      b[t] = *(const short8v*)(vt + base + (t * 16 + l15) * 64 + kk + quad * 8);
    }
#pragma unroll
    for (int mt = 0; mt < 4; ++mt)
#pragma unroll
      for (int nt = 0; nt < 4; ++nt)
        o[mt][nt] = __builtin_amdgcn_mfma_f32_16x16x32_bf16(a[mt], b[nt], o[mt][nt], 0, 0, 0);
  }

#pragma unroll
  for (int mt = 0; mt < 4; ++mt)
#pragma unroll
    for (int nt = 0; nt < 4; ++nt)
#pragma unroll
      for (int r = 0; r < 4; ++r) {
        int row = mt * 16 + quad * 4 + r;
        int col = nt * 16 + l15;
        float val = o[mt][nt][r] / lrow[mt][r];
        out[((long)win * 64 + row) * 512 + head * 64 + col] = f2bf(val);
      }
}

// ---------------- launch ---------------------------------------------------
extern "C" void kernel_launch(void* const* d_in, const int* in_sizes, int n_in,
                              void* d_out, int out_size, void* d_ws, size_t ws_size,
                              hipStream_t stream) {
  const float* x      = (const float*)d_in[0];
  const float* ln1_g  = (const float*)d_in[1];
  const float* ln1_b  = (const float*)d_in[2];
  const float* qkv_w  = (const float*)d_in[3];
  const float* qkv_b  = (const float*)d_in[4];
  const float* proj_w = (const float*)d_in[5];
  const float* proj_b = (const float*)d_in[6];
  const float* ln2_g  = (const float*)d_in[7];
  const float* ln2_b  = (const float*)d_in[8];
  const float* w1     = (const float*)d_in[9];
  const float* b1     = (const float*)d_in[10];
  const float* w2     = (const float*)d_in[11];
  const float* b2     = (const float*)d_in[12];

  // workspace layout (bytes); hid overlays attn_out+q+k+v (dead after proj)
  char* ws = (char*)d_ws;
  unsigned short* wt_qkv  = (unsigned short*)(ws + 0);          // 1536x512 bf16
  unsigned short* wt_proj = (unsigned short*)(ws + 1572864);    // 512x512
  unsigned short* wt_1    = (unsigned short*)(ws + 2097152);    // 2048x512
  unsigned short* wt_2    = (unsigned short*)(ws + 4194304);    // 512x2048
  float*          xo      = (float*)(ws + 8388608);             // 128 MiB fp32
  unsigned short* h       = (unsigned short*)(ws + 142606336);  // 64 MiB bf16 (h, then h2)
  unsigned short* attno   = (unsigned short*)(ws + 209715200);  // 64 MiB
  unsigned short* qb      = (unsigned short*)(ws + 276824064);  // 64 MiB
  unsigned short* kb      = (unsigned short*)(ws + 343932928);  // 64 MiB
  unsigned short* vb      = (unsigned short*)(ws + 411041792);  // 64 MiB
  unsigned short* hid     = (unsigned short*)(ws + 209715200);  // 256 MiB overlay
  float* out = (float*)d_out;

  wprep_kernel<<<3072, 256, 0, stream>>>(qkv_w, wt_qkv, 9, 512 * 1536, 1536);
  wprep_kernel<<<1024, 256, 0, stream>>>(proj_w, wt_proj, 9, 512 * 512, 512);
  wprep_kernel<<<4096, 256, 0, stream>>>(w1, wt_1, 9, 512 * 2048, 2048);
  wprep_kernel<<<4096, 256, 0, stream>>>(w2, wt_2, 11, 2048 * 512, 512);

  ln_kernel<<<16384, 256, 0, stream>>>(x, ln1_g, ln1_b, h, 1);
  gemm_bt<0><<<dim3(12, 512), 256, 0, stream>>>(h, wt_qkv, qkv_b, 512, qb, kb, vb, nullptr);
  attn_kernel<<<2048, 256, 0, stream>>>(qb, kb, vb, attno);
  gemm_bt<1><<<dim3(4, 512), 256, 0, stream>>>(attno, wt_proj, proj_b, 512, xo, nullptr, nullptr, x);
  ln_kernel<<<16384, 256, 0, stream>>>(xo, ln2_g, ln2_b, h, 0);
  gemm_bt<2><<<dim3(16, 512), 256, 0, stream>>>(h, wt_1, b1, 512, hid, nullptr, nullptr, nullptr);
  gemm_bt<3><<<dim3(4, 512), 256, 0, stream>>>(hid, wt_2, b2, 2048, out, nullptr, nullptr, xo);
}

// Round 3
// 1159.611 us; speedup vs baseline: 1.0751x; 1.0419x over previous
//
#include <hip/hip_runtime.h>
#include <hip/hip_bf16.h>

// Windowed 3D attention transformer block, MI355X bf16-MFMA implementation.
// Residual stream fp32; GEMM/attention compute bf16 in, fp32 accumulate.
// R1: global_load_lds 16B staging, XOR-swizzled chunks (conflict-free b128).
// R2: double-buffered K-loop (k+1 DMA in flight across compute k) — targets
//     the HBM-cold latency exposure at the barrier drain; wprep fused.

typedef __attribute__((ext_vector_type(4))) short short4v;
typedef __attribute__((ext_vector_type(8))) short short8v;
typedef __attribute__((ext_vector_type(4))) float f32x4;

__device__ __forceinline__ unsigned short f2bf(float f) {
  unsigned u = __float_as_uint(f);
  u += 0x7fffu + ((u >> 16) & 1u);   // RNE; inputs finite
  return (unsigned short)(u >> 16);
}

// async 16B global->LDS DMA; LDS dest = wave-uniform base + lane*16
__device__ __forceinline__ void gload_lds16(const unsigned short* g, unsigned short* l) {
  __builtin_amdgcn_global_load_lds(
      (const __attribute__((address_space(1))) unsigned int*)g,
      (__attribute__((address_space(3))) unsigned int*)l, 16, 0, 0);
}

// ---------------- weight prep (all 4 weights, one launch) ------------------
// wt element layout: [qkv 512x1536 ->786432][proj ->262144][w1 ->1048576][w2 ->1048576]
__global__ __launch_bounds__(256)
void wprep_all(const float* __restrict__ qkv_w, const float* __restrict__ proj_w,
               const float* __restrict__ w1, const float* __restrict__ w2,
               unsigned short* __restrict__ wt) {
  int idx = blockIdx.x * 256 + threadIdx.x;
  const float* w; int kbits, N, base;
  if (idx < 786432)       { w = qkv_w;  kbits = 9;  N = 1536; base = 0; }
  else if (idx < 1048576) { w = proj_w; kbits = 9;  N = 512;  base = 786432; }
  else if (idx < 2097152) { w = w1;     kbits = 9;  N = 2048; base = 1048576; }
  else                    { w = w2;     kbits = 11; N = 512;  base = 2097152; }
  int li = idx - base;
  int K = 1 << kbits;
  int n = li >> kbits, kk = li & (K - 1);
  wt[idx] = f2bf(w[(long)kk * N + n]);
}

// ---------------- LayerNorm (one wave per 512-elem row) --------------------
__global__ __launch_bounds__(256)
void ln_kernel(const float* __restrict__ src, const float* __restrict__ g,
               const float* __restrict__ bb, unsigned short* __restrict__ dst,
               const int gather) {
  const int lane = threadIdx.x & 63;
  const int row = blockIdx.x * 4 + (threadIdx.x >> 6);
  long srow;
  if (gather) {
    int n = row & 63, win = row >> 6;
    int w0 = win & 7, h0 = (win >> 3) & 7, d0 = (win >> 6) & 7, b2 = win >> 9;
    int dx = n & 3, dy = (n >> 2) & 3, dz = n >> 4;
    int od = (d0 * 4 + dz + 2) & 31, oh = (h0 * 4 + dy + 2) & 31, ow = (w0 * 4 + dx + 2) & 31;
    srow = (((long)b2 * 32 + od) * 32 + oh) * 32 + ow;
  } else {
    srow = row;
  }
  const float4* sp = (const float4*)(src + srow * 512);
  float4 x0 = sp[lane], x1 = sp[lane + 64];
  float sum = x0.x + x0.y + x0.z + x0.w + x1.x + x1.y + x1.z + x1.w;
  float sq  = x0.x*x0.x + x0.y*x0.y + x0.z*x0.z + x0.w*x0.w
            + x1.x*x1.x + x1.y*x1.y + x1.z*x1.z + x1.w*x1.w;
#pragma unroll
  for (int off = 1; off < 64; off <<= 1) {
    sum += __shfl_xor(sum, off, 64);
    sq  += __shfl_xor(sq, off, 64);
  }
  float mean = sum * (1.0f / 512.0f);
  float var  = sq * (1.0f / 512.0f) - mean * mean;
  float rstd = rsqrtf(var + 1e-5f);
  float4 g0 = ((const float4*)g)[lane], g1 = ((const float4*)g)[lane + 64];
  float4 b0 = ((const float4*)bb)[lane], b1v = ((const float4*)bb)[lane + 64];
  ushort4 o0, o1;
  o0.x = f2bf((x0.x - mean) * rstd * g0.x + b0.x);
  o0.y = f2bf((x0.y - mean) * rstd * g0.y + b0.y);
  o0.z = f2bf((x0.z - mean) * rstd * g0.z + b0.z);
  o0.w = f2bf((x0.w - mean) * rstd * g0.w + b0.w);
  o1.x = f2bf((x1.x - mean) * rstd * g1.x + b1v.x);
  o1.y = f2bf((x1.y - mean) * rstd * g1.y + b1v.y);
  o1.z = f2bf((x1.z - mean) * rstd * g1.z + b1v.z);
  o1.w = f2bf((x1.w - mean) * rstd * g1.w + b1v.w);
  *(ushort4*)(dst + (long)row * 512 + lane * 4) = o0;
  *(ushort4*)(dst + (long)row * 512 + 256 + lane * 4) = o1;
}

// ---------------- GEMM: C[M,N] = A[M,K](bf16) * Bt[N,K]^T + bias ----------
// 128x128 block tile, BK=32 double-buffered, 4 waves, 4x4 16x16x32 MFMA.
// DMA for tile k+1 issued at the top of compute(k); the compiler's
// vmcnt(0)-before-barrier then lands a full compute phase after issue.
template <int EPI>
__global__ __launch_bounds__(256)
void gemm_bt(const unsigned short* __restrict__ A,
             const unsigned short* __restrict__ Bt,
             const float* __restrict__ bias, int K,
             void* __restrict__ out0,
             unsigned short* __restrict__ out1,
             unsigned short* __restrict__ out2,
             const float* __restrict__ res) {
  __shared__ unsigned short As0[128 * 32], Bs0[128 * 32];
  __shared__ unsigned short As1[128 * 32], Bs1[128 * 32];
  const int tid = threadIdx.x;
  const int lane = tid & 63;
  const int wv = tid >> 6;
  const int quad = lane >> 4;
  const int l15 = lane & 15;
  const int wm = (wv >> 1) << 6;
  const int wn = (wv & 1) << 6;
  const long row0 = (long)blockIdx.y * 128;
  const long col0 = (long)blockIdx.x * 128;

  f32x4 acc[4][4] = {};

  // staging geometry: wave wv stages rows [c*64+wv*16, +16); lane covers
  // row (lane>>2), LDS chunk (lane&3); global chunk XOR-swizzled by row.
  const int srw = lane >> 2;
  const int sch = lane & 3;
  const int r0 = wv * 16 + srw, r1 = 64 + wv * 16 + srw;
  const unsigned short* gA0 = A  + (row0 + r0) * K + (sch ^ ((r0 >> 1) & 3)) * 8;
  const unsigned short* gA1 = A  + (row0 + r1) * K + (sch ^ ((r1 >> 1) & 3)) * 8;
  const unsigned short* gB0 = Bt + (col0 + r0) * K + (sch ^ ((r0 >> 1) & 3)) * 8;
  const unsigned short* gB1 = Bt + (col0 + r1) * K + (sch ^ ((r1 >> 1) & 3)) * 8;
  const int ld0 = (wv * 16) * 32, ld1 = (64 + wv * 16) * 32;

  // fragment LDS offsets (ushorts), fixed per lane
  int offA[4], offB[4];
#pragma unroll
  for (int t = 0; t < 4; ++t) {
    const int ra = wm + t * 16 + l15;
    offA[t] = ra * 32 + (quad ^ ((ra >> 1) & 3)) * 8;
    const int rb = wn + t * 16 + l15;
    offB[t] = rb * 32 + (quad ^ ((rb >> 1) & 3)) * 8;
  }

#define STAGE(AS, BS, kkx) do {                    \
    gload_lds16(gA0 + (kkx), &AS[ld0]);            \
    gload_lds16(gB0 + (kkx), &BS[ld0]);            \
    gload_lds16(gA1 + (kkx), &AS[ld1]);            \
    gload_lds16(gB1 + (kkx), &BS[ld1]);            \
  } while (0)

#define COMPUTE(AS, BS) do {                                                   \
    short8v af[4], bf[4];                                                      \
    _Pragma("unroll")                                                          \
    for (int t = 0; t < 4; ++t) {                                              \
      af[t] = *(const short8v*)&AS[offA[t]];                                   \
      bf[t] = *(const short8v*)&BS[offB[t]];                                   \
    }                                                                          \
    _Pragma("unroll")                                                          \
    for (int mt = 0; mt < 4; ++mt)                                             \
      _Pragma("unroll")                                                        \
      for (int nt = 0; nt < 4; ++nt)                                           \
        acc[mt][nt] = __builtin_amdgcn_mfma_f32_16x16x32_bf16(                 \
            af[mt], bf[nt], acc[mt][nt], 0, 0, 0);                             \
  } while (0)

  STAGE(As0, Bs0, 0);
  for (int kk = 0; kk < K; kk += 64) {       // K % 64 == 0 for all call sites
    __syncthreads();                         // drains stage(As0,kk)
    STAGE(As1, Bs1, kk + 32);                // in flight across compute(As0)
    COMPUTE(As0, Bs0);
    __syncthreads();                         // drains stage(As1)
    if (kk + 64 < K) STAGE(As0, Bs0, kk + 64);
    COMPUTE(As1, Bs1);
  }
#undef STAGE
#undef COMPUTE

#pragma unroll
  for (int mt = 0; mt < 4; ++mt) {
#pragma unroll
    for (int nt = 0; nt < 4; ++nt) {
#pragma unroll
      for (int r = 0; r < 4; ++r) {
        const long gr = row0 + wm + mt * 16 + quad * 4 + r;
        const long gc = col0 + wn + nt * 16 + l15;
        float val = acc[mt][nt][r] + bias[gc];
        if (EPI == 0) {
          int which = (int)(gc >> 9), rem = (int)gc & 511;
          int head = rem >> 6, hd = rem & 63;
          long win = gr >> 6, n = gr & 63;
          long base = (win * 8 + head) * 4096;
          unsigned short bv = f2bf(val);
          if (which == 0)      ((unsigned short*)out0)[base + n * 64 + hd] = bv;
          else if (which == 1) out1[base + n * 64 + hd] = bv;
          else                 out2[base + hd * 64 + n] = bv;   // v transposed
        } else if (EPI == 1) {
          int win = (int)(gr >> 6), n = (int)gr & 63;
          int w0 = win & 7, h0 = (win >> 3) & 7, d0 = (win >> 6) & 7, b2 = win >> 9;
          int dx = n & 3, dy = (n >> 2) & 3, dz = n >> 4;
          int od = (d0 * 4 + dz + 2) & 31, oh = (h0 * 4 + dy + 2) & 31, ow = (w0 * 4 + dx + 2) & 31;
          long addr = ((((long)b2 * 32 + od) * 32 + oh) * 32 + ow) * 512 + gc;
          ((float*)out0)[addr] = res[addr] + val;
        } else if (EPI == 2) {
          float ge = 0.5f * val * (1.0f + erff(val * 0.70710678118654752f));
          ((unsigned short*)out0)[gr * 2048 + gc] = f2bf(ge);
        } else {
          long addr = gr * 512 + gc;
          ((float*)out0)[addr] = res[addr] + val;
        }
      }
    }
  }
}

// ---------------- attention: one wave per (window, head) -------------------
__global__ __launch_bounds__(256)
void attn_kernel(const unsigned short* __restrict__ q,
                 const unsigned short* __restrict__ k,
                 const unsigned short* __restrict__ vt,
                 unsigned short* __restrict__ out) {
  __shared__ unsigned short Ps[4][64 * 72];
  const int lane = threadIdx.x & 63;
  const int wave = threadIdx.x >> 6;
  const int quad = lane >> 4;
  const int l15 = lane & 15;
  const int unit = blockIdx.x * 4 + wave;
  const int win = unit >> 3;
  const int head = unit & 7;
  const long base = (long)unit * 4096;

  f32x4 s[4][4] = {};
#pragma unroll
  for (int kk = 0; kk < 64; kk += 32) {
    short8v a[4], b[4];
#pragma unroll
    for (int t = 0; t < 4; ++t) {
      a[t] = *(const short8v*)(q + base + (t * 16 + l15) * 64 + kk + quad * 8);
      b[t] = *(const short8v*)(k + base + (t * 16 + l15) * 64 + kk + quad * 8);
    }
#pragma unroll
    for (int mt = 0; mt < 4; ++mt)
#pragma unroll
      for (int nt = 0; nt < 4; ++nt)
        s[mt][nt] = __builtin_amdgcn_mfma_f32_16x16x32_bf16(a[mt], b[nt], s[mt][nt], 0, 0, 0);
  }

  float lrow[4][4];
#pragma unroll
  for (int mt = 0; mt < 4; ++mt) {
#pragma unroll
    for (int r = 0; r < 4; ++r) {
      float v0 = s[mt][0][r] * 0.125f, v1 = s[mt][1][r] * 0.125f;
      float v2 = s[mt][2][r] * 0.125f, v3 = s[mt][3][r] * 0.125f;
      float mx = fmaxf(fmaxf(v0, v1), fmaxf(v2, v3));
#pragma unroll
      for (int off = 1; off < 16; off <<= 1) mx = fmaxf(mx, __shfl_xor(mx, off, 64));
      v0 = __expf(v0 - mx); v1 = __expf(v1 - mx);
      v2 = __expf(v2 - mx); v3 = __expf(v3 - mx);
      float sm = v0 + v1 + v2 + v3;
#pragma unroll
      for (int off = 1; off < 16; off <<= 1) sm += __shfl_xor(sm, off, 64);
      lrow[mt][r] = sm;
      int row = mt * 16 + quad * 4 + r;
      Ps[wave][row * 72 + 0 + l15]  = f2bf(v0);
      Ps[wave][row * 72 + 16 + l15] = f2bf(v1);
      Ps[wave][row * 72 + 32 + l15] = f2bf(v2);
      Ps[wave][row * 72 + 48 + l15] = f2bf(v3);
    }
  }
  __syncthreads();

  f32x4 o[4][4] = {};
#pragma unroll
  for (int kk = 0; kk < 64; kk += 32) {
    short8v a[4], b[4];
#pragma unroll
    for (int t = 0; t < 4; ++t) {
      a[t] = *(const short8v*)(&Ps[wave][(t * 16 + l15) * 72 + kk + quad * 8]);
      b[t] = *(const short8v*)(vt + base + (t * 16 + l15) * 64 + kk + quad * 8);
    }
#pragma unroll
    for (int mt = 0; mt < 4; ++mt)
#pragma unroll
      for (int nt = 0; nt < 4; ++nt)
        o[mt][nt] = __builtin_amdgcn_mfma_f32_16x16x32_bf16(a[mt], b[nt], o[mt][nt], 0, 0, 0);
  }

#pragma unroll
  for (int mt = 0; mt < 4; ++mt)
#pragma unroll
    for (int nt = 0; nt < 4; ++nt)
#pragma unroll
      for (int r = 0; r < 4; ++r) {
        int row = mt * 16 + quad * 4 + r;
        int col = nt * 16 + l15;
        float val = o[mt][nt][r] / lrow[mt][r];
        out[((long)win * 64 + row) * 512 + head * 64 + col] = f2bf(val);
      }
}

// ---------------- launch ---------------------------------------------------
extern "C" void kernel_launch(void* const* d_in, const int* in_sizes, int n_in,
                              void* d_out, int out_size, void* d_ws, size_t ws_size,
                              hipStream_t stream) {
  const float* x      = (const float*)d_in[0];
  const float* ln1_g  = (const float*)d_in[1];
  const float* ln1_b  = (const float*)d_in[2];
  const float* qkv_w  = (const float*)d_in[3];
  const float* qkv_b  = (const float*)d_in[4];
  const float* proj_w = (const float*)d_in[5];
  const float* proj_b = (const float*)d_in[6];
  const float* ln2_g  = (const float*)d_in[7];
  const float* ln2_b  = (const float*)d_in[8];
  const float* w1     = (const float*)d_in[9];
  const float* b1     = (const float*)d_in[10];
  const float* w2     = (const float*)d_in[11];
  const float* b2     = (const float*)d_in[12];

  // workspace layout (bytes); hid overlays attn_out+q+k+v (dead after proj)
  char* ws = (char*)d_ws;
  unsigned short* wt_all  = (unsigned short*)ws;
  unsigned short* wt_qkv  = (unsigned short*)(ws + 0);          // 1536x512 bf16
  unsigned short* wt_proj = (unsigned short*)(ws + 1572864);    // 512x512
  unsigned short* wt_1    = (unsigned short*)(ws + 2097152);    // 2048x512
  unsigned short* wt_2    = (unsigned short*)(ws + 4194304);    // 512x2048
  float*          xo      = (float*)(ws + 8388608);             // 128 MiB fp32
  unsigned short* h       = (unsigned short*)(ws + 142606336);  // 64 MiB bf16 (h, then h2)
  unsigned short* attno   = (unsigned short*)(ws + 209715200);  // 64 MiB
  unsigned short* qb      = (unsigned short*)(ws + 276824064);  // 64 MiB
  unsigned short* kb      = (unsigned short*)(ws + 343932928);  // 64 MiB
  unsigned short* vb      = (unsigned short*)(ws + 411041792);  // 64 MiB
  unsigned short* hid     = (unsigned short*)(ws + 209715200);  // 256 MiB overlay
  float* out = (float*)d_out;

  wprep_all<<<12288, 256, 0, stream>>>(qkv_w, proj_w, w1, w2, wt_all);

  ln_kernel<<<16384, 256, 0, stream>>>(x, ln1_g, ln1_b, h, 1);
  gemm_bt<0><<<dim3(12, 512), 256, 0, stream>>>(h, wt_qkv, qkv_b, 512, qb, kb, vb, nullptr);
  attn_kernel<<<2048, 256, 0, stream>>>(qb, kb, vb, attno);
  gemm_bt<1><<<dim3(4, 512), 256, 0, stream>>>(attno, wt_proj, proj_b, 512, xo, nullptr, nullptr, x);
  ln_kernel<<<16384, 256, 0, stream>>>(xo, ln2_g, ln2_b, h, 0);
  gemm_bt<2><<<dim3(16, 512), 256, 0, stream>>>(h, wt_1, b1, 512, hid, nullptr, nullptr, nullptr);
  gemm_bt<3><<<dim3(4, 512), 256, 0, stream>>>(hid, wt_2, b2, 2048, out, nullptr, nullptr, xo);
}